// Round 6
// baseline (47.065 us; speedup 1.0000x reference)
//
#include <hip/hip_runtime.h>

#define FEAT    4096
#define NACT    512
#define THREADS 256
#define EPT     16
#define KRANK   (FEAT - NACT)   // 3584: ascending rank of smallest kept elem
#define FLO     0.8f
#define FHI     1.5f
#define RBINS   1024
#define MAXCAND 64

typedef float f32x4 __attribute__((ext_vector_type(4)));

// Order-preserving float32 <-> uint32 key transform (fallback path only).
__device__ __forceinline__ unsigned f2key(float f) {
    unsigned b = __float_as_uint(f);
    return (b & 0x80000000u) ? ~b : (b | 0x80000000u);
}
__device__ __forceinline__ float key2f(unsigned k) {
    unsigned b = (k & 0x80000000u) ? (k & 0x7fffffffu) : ~k;
    return __uint_as_float(b);
}

__global__ __launch_bounds__(THREADS, 8) void normactive_kernel(
        const float* __restrict__ in, float* __restrict__ out) {
    const int tid  = threadIdx.x;
    const int wid  = tid >> 6;
    const int lane = tid & 63;
    const float* rp = in  + (size_t)blockIdx.x * FEAT;
    float*       op = out + (size_t)blockIdx.x * FEAT;

    __shared__ __align__(16) unsigned buf[4096];   // 1024-bin range hist; fallback 4096-bin hist + compact
    __shared__ unsigned long long cand[MAXCAND];
    __shared__ unsigned wsum[4];
    __shared__ unsigned s_nhi, s_n, s_B, s_kk, s_cnt, s_tidx;
    __shared__ float s_vb;

    // ---- Load row into registers (coalesced float4).
    float xv[EPT];
    #pragma unroll
    for (int c = 0; c < 4; ++c) {
        float4 t = reinterpret_cast<const float4*>(rp)[c * THREADS + tid];
        xv[4*c+0] = t.x; xv[4*c+1] = t.y; xv[4*c+2] = t.z; xv[4*c+3] = t.w;
    }

    // ---- Zero 1024-bin histogram + counters.
    uint4 z; z.x = z.y = z.z = z.w = 0u;
    reinterpret_cast<uint4*>(buf)[tid] = z;        // 256 * 16B = 1024 words
    if (tid == 0) { s_nhi = 0; s_n = 0; }
    __syncthreads();

    // ---- Classify: count x > FHI; histogram x in (FLO, FHI] into 1024 bins.
    const float invw = (float)RBINS / (FHI - FLO);
    unsigned chi = 0;
    unsigned ub[EPT];                              // per-element bin (0xffffffff = not in range)
    #pragma unroll
    for (int e = 0; e < EPT; ++e) {
        float x = xv[e];
        bool hi = (x > FHI);
        chi += hi ? 1u : 0u;
        unsigned b = 0xffffffffu;
        if (x > FLO && !hi) {
            int bi = (int)((x - FLO) * invw);      // >= 0 since x > FLO; monotone in x
            bi = bi < (RBINS - 1) ? bi : (RBINS - 1);
            b = (unsigned)bi;
            atomicAdd(&buf[bi], 1u);
        }
        ub[e] = b;
    }
    #pragma unroll
    for (int off = 32; off >= 1; off >>= 1)
        chi += __shfl_xor(chi, (unsigned)off, 64);
    if (lane == 0) atomicAdd(&s_nhi, chi);
    __syncthreads();

    const int nHi = (int)s_nhi;

    // ---- Scan: thread t owns bins [4t, 4t+4); one b128 read + wave scan.
    uint4 q = reinterpret_cast<const uint4*>(buf)[tid];
    unsigned s = q.x + q.y + q.z + q.w;
    unsigned inc = s;
    #pragma unroll
    for (int off = 1; off < 64; off <<= 1) {
        unsigned n = __shfl_up(inc, (unsigned)off, 64);
        if (lane >= off) inc += n;
    }
    if (lane == 63) wsum[wid] = inc;
    __syncthreads();
    unsigned base = 0;
    #pragma unroll
    for (int w = 0; w < 3; ++w) if (w < wid) base += wsum[w];
    const int nIn = (int)(wsum[0] + wsum[1] + wsum[2] + wsum[3]);
    const unsigned excl = base + inc - s;          // asc prefix at bin 4*tid (within range region)

    const int nLo  = FEAT - nIn - nHi;
    const int need = NACT - nHi;                   // kept elements still needed from binned region
    const int kkb  = KRANK - nLo;                  // asc rank of boundary within binned region

    // mode: 0 = boundary in an interior bin, 1 = threshold exactly at FHI, 2 = generic fallback
    int mode = (need > 0 && kkb >= 0 && kkb < nIn) ? 0 : ((need == 0) ? 1 : 2);

    if (mode == 0) {
        unsigned bq[4] = {q.x, q.y, q.z, q.w};
        unsigned run = excl;
        #pragma unroll
        for (int i = 0; i < 4; ++i) {
            if ((unsigned)kkb >= run && (unsigned)kkb < run + bq[i]) {
                s_B   = (unsigned)(4 * tid + i);
                s_kk  = (unsigned)kkb - run;
                s_cnt = bq[i];
            }
            run += bq[i];
        }
    }
    __syncthreads();

    if (mode == 0 && s_cnt > MAXCAND) mode = 2;    // uniform

    if (mode == 0) {
        const unsigned B = s_B, kk = s_kk, cnt = s_cnt;
        // Compact boundary-bin candidates as (bits, idx); all in-range values are
        // positive so uint-bit order == float order. (value, idx) lexicographic
        // == reference stable-sort tie rule (largest indices kept).
        #pragma unroll
        for (int e = 0; e < EPT; ++e) {
            if (ub[e] == B) {
                unsigned idx = (unsigned)((e >> 2) * 1024 + tid * 4 + (e & 3));
                unsigned pos = atomicAdd(&s_n, 1u);
                cand[pos] = ((unsigned long long)__float_as_uint(xv[e]) << 32) | idx;
            }
        }
        __syncthreads();
        if (tid < (int)cnt) {
            unsigned long long my = cand[tid];
            unsigned r = 0;
            for (unsigned j = 0; j < cnt; ++j) r += (cand[j] < my) ? 1u : 0u;
            if (r == kk) {                          // exactly one thread matches
                s_vb   = __uint_as_float((unsigned)(my >> 32));
                s_tidx = (unsigned)(my & 0xffffffffu);
            }
        }
    } else if (mode == 1) {
        // Exactly nHi == 512: keep = (x > FHI); no ties kept.
        if (tid == 0) { s_vb = FHI; s_tidx = (unsigned)FEAT; }
    } else {
        // ---- Generic fallback (never taken for this input): 12-bit key hist +
        // compact + rank-select (R4's verified algorithm). Keys recomputed
        // inline from xv so this path adds no VGPR pressure to the hot path.
        #pragma unroll
        for (int i = 0; i < 4; ++i)
            reinterpret_cast<uint4*>(buf)[i * THREADS + tid] = z;
        if (tid == 0) s_n = 0;
        __syncthreads();
        #pragma unroll
        for (int e = 0; e < EPT; ++e)
            atomicAdd(&buf[f2key(xv[e]) >> 20], 1u);
        __syncthreads();
        unsigned tot = 0;
        #pragma unroll
        for (int i = 0; i < 16; ++i) tot += buf[16 * tid + i];
        unsigned inc2 = tot;
        #pragma unroll
        for (int off = 1; off < 64; off <<= 1) {
            unsigned n = __shfl_up(inc2, (unsigned)off, 64);
            if (lane >= off) inc2 += n;
        }
        if (lane == 63) wsum[wid] = inc2;
        __syncthreads();
        unsigned b2 = 0;
        #pragma unroll
        for (int w = 0; w < 3; ++w) if (w < wid) b2 += wsum[w];
        unsigned ex2 = b2 + inc2 - tot;
        if ((unsigned)KRANK >= ex2 && (unsigned)KRANK < ex2 + tot) {
            unsigned run = ex2;
            #pragma unroll
            for (int i = 0; i < 16; ++i) {
                unsigned c = buf[16 * tid + i];
                if ((unsigned)KRANK >= run && (unsigned)KRANK < run + c) {
                    s_B   = (unsigned)(16 * tid + i);
                    s_kk  = (unsigned)KRANK - run;
                    s_cnt = c;
                }
                run += c;
            }
        }
        __syncthreads();
        const unsigned P = s_B, kk2 = s_kk, cnt2 = s_cnt;
        #pragma unroll
        for (int e = 0; e < EPT; ++e) {
            unsigned k = f2key(xv[e]);
            if ((k >> 20) == P) {
                unsigned idx = (unsigned)((e >> 2) * 1024 + tid * 4 + (e & 3));
                unsigned pos = atomicAdd(&s_n, 1u);
                buf[pos] = (k << 12) | idx;
            }
        }
        __syncthreads();
        for (unsigned slot = tid; slot < cnt2; slot += THREADS) {
            unsigned my = buf[slot];
            unsigned r = 0;
            for (unsigned j = 0; j < cnt2; ++j) r += (buf[j] < my) ? 1u : 0u;
            if (r == kk2) {
                s_vb   = key2f((P << 20) | (my >> 12));   // candidates share top-12 bits P
                s_tidx = my & 0xfffu;
            }
        }
    }
    __syncthreads();

    const float vb = s_vb;
    const int   ti = (int)s_tidx;

    // ---- Output: keep iff x > vb, or x == vb with idx >= ti. Exact ×8 scale.
    // Non-temporal stores: output is write-once/never-read -> don't let it
    // evict the (re-read every replay) input from L2/Infinity Cache.
    #pragma unroll
    for (int c = 0; c < 4; ++c) {
        const int bidx = c * 1024 + tid * 4;
        float a0 = xv[4*c+0], a1 = xv[4*c+1], a2 = xv[4*c+2], a3 = xv[4*c+3];
        f32x4 o;
        o.x = (a0 > vb || (a0 == vb && bidx + 0 >= ti)) ? a0 * 8.0f : 0.0f;
        o.y = (a1 > vb || (a1 == vb && bidx + 1 >= ti)) ? a1 * 8.0f : 0.0f;
        o.z = (a2 > vb || (a2 == vb && bidx + 2 >= ti)) ? a2 * 8.0f : 0.0f;
        o.w = (a3 > vb || (a3 == vb && bidx + 3 >= ti)) ? a3 * 8.0f : 0.0f;
        __builtin_nontemporal_store(o, reinterpret_cast<f32x4*>(op) + c * THREADS + tid);
    }
}

extern "C" void kernel_launch(void* const* d_in, const int* in_sizes, int n_in,
                              void* d_out, int out_size, void* d_ws, size_t ws_size,
                              hipStream_t stream) {
    const float* feat = (const float*)d_in[0];
    float* out = (float*)d_out;
    const int batch = in_sizes[0] / FEAT;  // 8192
    normactive_kernel<<<batch, THREADS, 0, stream>>>(feat, out);
}